// Round 17
// baseline (182.952 us; speedup 1.0000x reference)
//
#include <hip/hip_runtime.h>

typedef __attribute__((ext_vector_type(8))) short short8;
typedef __attribute__((ext_vector_type(4))) float f32x4;
typedef __attribute__((ext_vector_type(16))) float f32x16;

#define I2ROWS 40
#define I2STRIDE (I2ROWS * 128)     // 5120 shorts / buffer (phase 2)
#define P1ROWS 72
#define P1STRIDE (P1ROWS * 128)     // 9216 shorts / buffer (phase 1)
#define GWOFF 1056768               // byte offset of tab[] in d_ws (after gw16)

template<int N> struct IC { static constexpr int v = N; };

static __device__ __forceinline__ unsigned packbf(float hi, float lo) {
    return __builtin_amdgcn_perm(__float_as_uint(hi) + 0x8000u,
                                 __float_as_uint(lo) + 0x8000u, 0x07060302u);
}
static __device__ __forceinline__ unsigned short one_bf(float f) {
    return (unsigned short)((__float_as_uint(f) + 0x8000u) >> 16);
}
static __device__ __forceinline__ float bflo(unsigned u) { return __uint_as_float(u << 16); }
static __device__ __forceinline__ float bfhi(unsigned u) { return __uint_as_float(u & 0xffff0000u); }

// bf16 image swizzle: 8-short (16B) granular XOR
static __device__ __forceinline__ int swzB(int row, int c) {
    return row * 128 + (c ^ ((row & 15) << 3));
}
// fp32 master swizzle (phase 1): 2-float granular XOR
static __device__ __forceinline__ int swzH(int t, int o) {
    return (t * 128 + o) ^ ((t & 15) << 1);
}

// ============ KERNEL 0: embedding+reducer collapsed tables (weight-only) ============
__global__ __launch_bounds__(256, 1)
void vgt_tab(const float* __restrict__ emb_w, const float* __restrict__ red_w,
             float* __restrict__ tab)
{
    int i = blockIdx.x * 256 + threadIdx.x;
    if (i >= 2560) return;
    int o = i / 20, col = i % 20, v = (col < 10) ? col : (col - 10);
    const float4* rw = (const float4*)(red_w + o * 256 + ((col < 10) ? 0 : 128));
    const float4* ew = (const float4*)(emb_w + v * 128);
    float s = 0.f;
#pragma unroll 8
    for (int c2 = 0; c2 < 32; ++c2) {
        float4 a = rw[c2], e = ew[c2];
        s += a.x * e.x + a.y * e.y + a.z * e.z + a.w * e.w;
    }
    tab[i] = s;
}

// ============ PHASE 1: steps 0-7 chunked with halo, 128 blocks x 256 thr ============
__global__ __launch_bounds__(256, 1)
void vgt_phase1(const int* __restrict__ x,
                const float* __restrict__ red_b,
                const float* __restrict__ conv_w,
                const float* __restrict__ conv_b,
                const float* __restrict__ tab,
                unsigned short* __restrict__ gw16)
{
    __shared__ short imgC[2 * P1STRIDE];   // 36864 B ping-pong, rows = t - ws + 2
    __shared__ float hrFC[64 * 128];       // 32768 B fp32 master, rows = t - ws
    __shared__ float tabS[2560];
    __shared__ float cbS[128];
    __shared__ float rbS[128];
    __shared__ int   xbS[256];

    const int bid = blockIdx.x, b = bid >> 2, c = bid & 3;
    const int os = c * 33, oe = (os + 33 > 129) ? 129 : (os + 33), ws = os - 14;
    const int tid = threadIdx.x, lane = tid & 63;
    const int wm = tid >> 6, obase = wm * 32;
    const int l31 = lane & 31, lhi = lane >> 5;

    for (int i = tid; i < P1STRIDE; i += 256) ((int*)imgC)[i] = 0;   // both buffers
    for (int i = tid; i < 2560; i += 256) tabS[i] = tab[i];
    xbS[tid] = x[b * 256 + tid];
    if (tid < 128) { cbS[tid] = conv_b[tid]; rbS[tid] = red_b[tid]; }

    short8 aw[24];
#pragma unroll
    for (int s = 0; s < 24; ++s) {
        int kk = s >> 3, cb = s & 7;
        int o = obase + l31, c0 = cb * 16 + lhi * 8;
        short8 v;
#pragma unroll
        for (int j = 0; j < 8; ++j)
            v[j] = (short)one_bf(conv_w[(o * 128 + c0 + j) * 3 + kk]);
        aw[s] = v;
    }
    __syncthreads();

    for (int i = tid; i < 68 * 64; i += 256) {
        int rr = i >> 6, o2 = (i & 63) * 2, t = ws - 2 + rr;
        float v0 = 0.f, v1 = 0.f;
        if (t >= 0 && t < 128) {
            int x1 = xbS[t], x2 = xbS[t + 128];
            v0 = tabS[o2 * 20 + x1] + tabS[o2 * 20 + 10 + x2] + rbS[o2];
            v0 = v0 > 0.f ? v0 : 0.f;
            v1 = tabS[(o2 + 1) * 20 + x1] + tabS[(o2 + 1) * 20 + 10 + x2] + rbS[o2 + 1];
            v1 = v1 > 0.f ? v1 : 0.f;
            *(unsigned*)&imgC[swzB(rr, o2)] = packbf(v1, v0);
        }
        int rm = rr - 2;
        if (rm >= 0 && rm < 64) *(float2*)&hrFC[swzH(rm, o2)] = make_float2(v0, v1);
    }
    __syncthreads();

    int cur = 0;
    auto tileC = [&](auto DDC, int n, const short* src, short* dst) {
        constexpr int DD = decltype(DDC)::v;
        f32x16 a0, a1, a2;
#pragma unroll
        for (int g = 0; g < 4; ++g) {
            float4 bv = *(const float4*)&cbS[obase + 8 * g + 4 * lhi];
            a0[4*g+0] = bv.x; a0[4*g+1] = bv.y; a0[4*g+2] = bv.z; a0[4*g+3] = bv.w;
            a1[4*g+0] = 0.f; a1[4*g+1] = 0.f; a1[4*g+2] = 0.f; a1[4*g+3] = 0.f;
            a2[4*g+0] = 0.f; a2[4*g+1] = 0.f; a2[4*g+2] = 0.f; a2[4*g+3] = 0.f;
        }
        const int rb0 = n * 32 + l31 + 2 - DD;
#define TAPC(KK, ACC) { const int row = rb0 + KK * DD; \
    _Pragma("unroll") for (int cb = 0; cb < 8; ++cb) { \
        short8 bf = *(const short8*)&src[swzB(row, cb * 16 + lhi * 8)]; \
        ACC = __builtin_amdgcn_mfma_f32_32x32x16_bf16(aw[KK * 8 + cb], bf, ACC, 0, 0, 0); } }
        TAPC(0, a0) TAPC(1, a1) TAPC(2, a2)
#undef TAPC
        const int t = ws + n * 32 + l31;
        if (t >= 0 && t <= 128) {
            const int rm = n * 32 + l31;
#pragma unroll
            for (int g = 0; g < 4; ++g) {
                const int o4 = obase + 8 * g + 4 * lhi;
                const int h0 = swzH(rm, o4), h1 = swzH(rm, o4 + 2);
                float2 ha = *(const float2*)&hrFC[h0];
                float2 hb = *(const float2*)&hrFC[h1];
                ha.x += fmaxf(a0[4*g+0] + a1[4*g+0] + a2[4*g+0], 0.f);
                ha.y += fmaxf(a0[4*g+1] + a1[4*g+1] + a2[4*g+1], 0.f);
                hb.x += fmaxf(a0[4*g+2] + a1[4*g+2] + a2[4*g+2], 0.f);
                hb.y += fmaxf(a0[4*g+3] + a1[4*g+3] + a2[4*g+3], 0.f);
                *(float2*)&hrFC[h0] = ha;
                *(float2*)&hrFC[h1] = hb;
                *(uint2*)&dst[swzB(rm + 2, o4)] =
                    make_uint2(packbf(ha.y, ha.x), packbf(hb.y, hb.x));
            }
        }
    };
    auto step1 = [&](auto DDC) {
        const short* src = imgC + cur * P1STRIDE;
        short*       dst = imgC + (cur ^ 1) * P1STRIDE;
        tileC(DDC, 0, src, dst);
        tileC(DDC, 1, src, dst);
        __syncthreads();
        cur ^= 1;
    };
    for (int i = 0; i < 4; ++i) step1(IC<1>{});
    for (int i = 0; i < 4; ++i) step1(IC<2>{});

    for (int i = tid; i < (oe - os) * 128; i += 256) {
        int t = os + (i >> 7), o = i & 127;
        gw16[b * 16512 + t * 128 + o] = one_bf(hrFC[swzH(t - ws, o)]);
    }
}

// ===== PHASE 2: 123 d=4 steps; 128 blocks x 512 thr; ch-split wave pairs on 32-o tiles =====
__global__ __launch_bounds__(512, 1)
void vgt_phase2(const float* __restrict__ conv_w,
                const float* __restrict__ conv_b,
                const float* __restrict__ out_w,
                const float* __restrict__ out_b,
                const unsigned short* __restrict__ gw16,
                float* __restrict__ out)
{
    __shared__ short    img2[2 * I2STRIDE];   // 20480 B ping-pong; rows 0, 34+ stay zero
    __shared__ float    pbuf[6 * 1024];       // 24576 B partial-sum exchange (SoA, 6 comps)
    __shared__ float    hrF2[33 * 128];       // final h slice (plain layout)
    __shared__ unsigned owP[10][64];
    __shared__ float    cbS[128];
    __shared__ float    obS[16];

    const int bid = blockIdx.x, b = bid >> 2, r = bid & 3;
    const int tid = threadIdx.x, lane = tid & 63;
    const int wv = tid >> 6;
    const int pr = wv & 3;            // o-pair: o in [pr*32, pr*32+32)
    const int role = wv >> 2;         // 0 = reader (ch 0..63), 1 = writer (ch 64..127)
    const int obase = pr * 32;
    const int chbase = role * 64;
    const int l15 = lane & 15, g4 = lane >> 4;

    for (int i = tid; i < I2STRIDE; i += 512) ((int*)img2)[i] = 0;   // both buffers
    if (tid < 128) cbS[tid] = conv_b[tid];
    if (tid < 16)  obS[tid] = (tid < 10) ? out_b[tid] : 0.f;
    for (int i = tid; i < 640; i += 512) {
        int v = i >> 6, j = i & 63;
        owP[v][j] = packbf(out_w[v * 128 + 2 * j + 1], out_w[v * 128 + 2 * j]);
    }

    // A fragments: aw[s*2+mt]; s = kk*2+cb (kk 0..2, cb 0..1 of this role's 64ch); mt = 16-o tile
    short8 aw[12];
#pragma unroll
    for (int s = 0; s < 6; ++s) {
        int kk = s >> 1, cb = s & 1;
        int c0 = chbase + cb * 32 + g4 * 8;
#pragma unroll
        for (int mt = 0; mt < 2; ++mt) {
            int o = obase + mt * 16 + l15;
            short8 v;
#pragma unroll
            for (int j = 0; j < 8; ++j)
                v[j] = (short)one_bf(conv_w[(o * 128 + c0 + j) * 3 + kk]);
            aw[s * 2 + mt] = v;
        }
    }

    const unsigned short* gb = gw16 + b * 16512;

    // masters: reader holds main hm (4 tiles x 4), writer holds appendix hA (2 tiles x 4)
    float hm00[4], hm01[4], hm10[4], hm11[4];   // [tt][mt]
    float hA0[4], hA1[4];
    if (role == 0) {
#pragma unroll
        for (int q = 0; q < 4; ++q) {
            hm00[q] = bflo((unsigned)gb[(4 * l15 + r) * 128 + obase + g4 * 4 + q]);
            hm01[q] = bflo((unsigned)gb[(4 * l15 + r) * 128 + obase + 16 + g4 * 4 + q]);
            hm10[q] = bflo((unsigned)gb[(4 * (16 + l15) + r) * 128 + obase + g4 * 4 + q]);
            hm11[q] = bflo((unsigned)gb[(4 * (16 + l15) + r) * 128 + obase + 16 + g4 * 4 + q]);
        }
    } else {
#pragma unroll
        for (int q = 0; q < 4; ++q) {
            hA0[q] = (r == 0) ? bflo((unsigned)gb[16384 + obase + g4 * 4 + q]) : 0.f;
            hA1[q] = (r == 0) ? bflo((unsigned)gb[16384 + obase + 16 + g4 * 4 + q]) : 0.f;
        }
    }

    // resident LDS byte addresses (tt=1 via +4096 imm; buffer flip via +10240 imm)
    int aM[6], aA[4], aW00, aW01, aW10, aW11, aWA0, aWA1;
#pragma unroll
    for (int s = 0; s < 6; ++s)
        aM[s] = 2 * swzB(l15 + (s >> 1), chbase + (s & 1) * 32 + g4 * 8);
#pragma unroll
    for (int s = 0; s < 4; ++s)
        aA[s] = 2 * swzB(32 + (s >> 1), chbase + (s & 1) * 32 + g4 * 8);
    aW00 = 2 * swzB(l15 + 1, obase + g4 * 4);
    aW01 = 2 * swzB(l15 + 1, obase + 16 + g4 * 4);
    aW10 = 2 * swzB(16 + l15 + 1, obase + g4 * 4);
    aW11 = 2 * swzB(16 + l15 + 1, obase + 16 + g4 * 4);
    aWA0 = 2 * swzB(33, obase + g4 * 4);
    aWA1 = 2 * swzB(33, obase + 16 + g4 * 4);
    const int pAddr = pr * 1024 + lane * 16;    // bytes into pbuf; comps at +4096*c

    __syncthreads();   // img2 zeroed, cbS ready

    float bb[8];       // bias: [mt*4+q]
#pragma unroll
    for (int q = 0; q < 4; ++q) {
        bb[q]     = cbS[obase + g4 * 4 + q];
        bb[4 + q] = cbS[obase + 16 + g4 * 4 + q];
    }

    // populate img2 buffer 0
    for (int i = tid; i < 33 * 64; i += 512) {
        int tp = i >> 6, o2 = (i & 63) * 2;
        if (tp < 32) {
            unsigned u0 = gb[(4 * tp + r) * 128 + o2], u1 = gb[(4 * tp + r) * 128 + o2 + 1];
            *(unsigned*)&img2[swzB(tp + 1, o2)] = (u1 << 16) | u0;
        } else if (r == 0) {
            unsigned u0 = gb[16384 + o2], u1 = gb[16384 + o2 + 1];
            *(unsigned*)&img2[swzB(33, o2)] = (u1 << 16) | u0;
        }
    }
    __syncthreads();

    char* const ibase = (char*)img2;
    char* const pB = (char*)pbuf;

    auto stepF = [&](auto SO_, auto DO_) {
        constexpr int SO = decltype(SO_)::v;
        constexpr int DO = decltype(DO_)::v;
        f32x4 a00, a01, a10, a11;     // [tt][mt], this role's ch-half
#pragma unroll
        for (int q = 0; q < 4; ++q) { a00[q] = 0.f; a01[q] = 0.f; a10[q] = 0.f; a11[q] = 0.f; }
#pragma unroll
        for (int s = 0; s < 6; ++s) {
            short8 b0 = *(const short8*)(ibase + aM[s] + SO);
            short8 b1 = *(const short8*)(ibase + aM[s] + 4096 + SO);
            a00 = __builtin_amdgcn_mfma_f32_16x16x32_bf16(aw[s * 2 + 0], b0, a00, 0, 0, 0);
            a01 = __builtin_amdgcn_mfma_f32_16x16x32_bf16(aw[s * 2 + 1], b0, a01, 0, 0, 0);
            a10 = __builtin_amdgcn_mfma_f32_16x16x32_bf16(aw[s * 2 + 0], b1, a10, 0, 0, 0);
            a11 = __builtin_amdgcn_mfma_f32_16x16x32_bf16(aw[s * 2 + 1], b1, a11, 0, 0, 0);
        }
        f32x4 ap0, ap1;               // appendix partial, this role's ch-half (r==0)
        if (role == 1) {
            // writer: publish main partials (comps 0..3)
            *(f32x4*)(pB + pAddr)         = a00;
            *(f32x4*)(pB + pAddr + 4096)  = a01;
            *(f32x4*)(pB + pAddr + 8192)  = a10;
            *(f32x4*)(pB + pAddr + 12288) = a11;
            if (r == 0) {
#pragma unroll
                for (int q = 0; q < 4; ++q) { ap0[q] = 0.f; ap1[q] = 0.f; }
#pragma unroll
                for (int s = 0; s < 4; ++s) {
                    short8 bf = *(const short8*)(ibase + aA[s] + SO);
                    ap0 = __builtin_amdgcn_mfma_f32_16x16x32_bf16(aw[s * 2 + 0], bf, ap0, 0, 0, 0);
                    ap1 = __builtin_amdgcn_mfma_f32_16x16x32_bf16(aw[s * 2 + 1], bf, ap1, 0, 0, 0);
                }
            }
        } else if (r == 0) {
            // reader: compute its appendix half and publish (comps 4,5)
#pragma unroll
            for (int q = 0; q < 4; ++q) { ap0[q] = 0.f; ap1[q] = 0.f; }
#pragma unroll
            for (int s = 0; s < 4; ++s) {
                short8 bf = *(const short8*)(ibase + aA[s] + SO);
                ap0 = __builtin_amdgcn_mfma_f32_16x16x32_bf16(aw[s * 2 + 0], bf, ap0, 0, 0, 0);
                ap1 = __builtin_amdgcn_mfma_f32_16x16x32_bf16(aw[s * 2 + 1], bf, ap1, 0, 0, 0);
            }
            *(f32x4*)(pB + pAddr + 16384) = ap0;
            *(f32x4*)(pB + pAddr + 20480) = ap1;
        }
        __syncthreads();   // partials visible

        if (role == 0) {
            // reader: combine writer's main partials, update masters, commit to dst
            f32x4 p00 = *(const f32x4*)(pB + pAddr);
            f32x4 p01 = *(const f32x4*)(pB + pAddr + 4096);
            f32x4 p10 = *(const f32x4*)(pB + pAddr + 8192);
            f32x4 p11 = *(const f32x4*)(pB + pAddr + 12288);
#pragma unroll
            for (int q = 0; q < 4; ++q) hm00[q] += fmaxf(a00[q] + p00[q] + bb[q], 0.f);
            *(uint2*)(ibase + aW00 + DO) =
                make_uint2(packbf(hm00[1], hm00[0]), packbf(hm00[3], hm00[2]));
#pragma unroll
            for (int q = 0; q < 4; ++q) hm01[q] += fmaxf(a01[q] + p01[q] + bb[4 + q], 0.f);
            *(uint2*)(ibase + aW01 + DO) =
                make_uint2(packbf(hm01[1], hm01[0]), packbf(hm01[3], hm01[2]));
#pragma unroll
            for (int q = 0; q < 4; ++q) hm10[q] += fmaxf(a10[q] + p10[q] + bb[q], 0.f);
            *(uint2*)(ibase + aW10 + DO) =
                make_uint2(packbf(hm10[1], hm10[0]), packbf(hm10[3], hm10[2]));
#pragma unroll
            for (int q = 0; q < 4; ++q) hm11[q] += fmaxf(a11[q] + p11[q] + bb[4 + q], 0.f);
            *(uint2*)(ibase + aW11 + DO) =
                make_uint2(packbf(hm11[1], hm11[0]), packbf(hm11[3], hm11[2]));
        } else if (r == 0) {
            // writer: combine reader's appendix partials, update hA, commit row 33
            f32x4 q0 = *(const f32x4*)(pB + pAddr + 16384);
            f32x4 q1 = *(const f32x4*)(pB + pAddr + 20480);
#pragma unroll
            for (int q = 0; q < 4; ++q) hA0[q] += fmaxf(ap0[q] + q0[q] + bb[q], 0.f);
#pragma unroll
            for (int q = 0; q < 4; ++q) hA1[q] += fmaxf(ap1[q] + q1[q] + bb[4 + q], 0.f);
            if (l15 == 0) {
                *(uint2*)(ibase + aWA0 + DO) =
                    make_uint2(packbf(hA0[1], hA0[0]), packbf(hA0[3], hA0[2]));
                *(uint2*)(ibase + aWA1 + DO) =
                    make_uint2(packbf(hA1[1], hA1[0]), packbf(hA1[3], hA1[2]));
            }
        }
        __syncthreads();   // dst complete
    };

    for (int i2 = 0; i2 < 61; ++i2) {
        stepF(IC<0>{}, IC<10240>{});
        stepF(IC<10240>{}, IC<0>{});
    }
    stepF(IC<0>{}, IC<10240>{});   // 123rd step

    // dump masters to LDS (plain layout) for the head
    if (role == 0) {
        *(float4*)&hrF2[l15 * 128 + obase + g4 * 4] =
            make_float4(hm00[0], hm00[1], hm00[2], hm00[3]);
        *(float4*)&hrF2[l15 * 128 + obase + 16 + g4 * 4] =
            make_float4(hm01[0], hm01[1], hm01[2], hm01[3]);
        *(float4*)&hrF2[(16 + l15) * 128 + obase + g4 * 4] =
            make_float4(hm10[0], hm10[1], hm10[2], hm10[3]);
        *(float4*)&hrF2[(16 + l15) * 128 + obase + 16 + g4 * 4] =
            make_float4(hm11[0], hm11[1], hm11[2], hm11[3]);
    } else if (r == 0 && l15 == 0) {
        *(float4*)&hrF2[32 * 128 + obase + g4 * 4] =
            make_float4(hA0[0], hA0[1], hA0[2], hA0[3]);
        *(float4*)&hrF2[32 * 128 + obase + 16 + g4 * 4] =
            make_float4(hA1[0], hA1[1], hA1[2], hA1[3]);
    }
    __syncthreads();

    // output head: out[b, 4*t'+r, v]
    const int g4h = tid & 3;
    const int tt = tid >> 2;
    const int TR = (r == 0) ? 33 : 32;
    if (tt < TR) {
        float hq[32];
#pragma unroll
        for (int j = 0; j < 8; ++j) {
            float4 v = *(const float4*)&hrF2[tt * 128 + 32 * g4h + 4 * j];
            hq[4*j+0] = v.x; hq[4*j+1] = v.y; hq[4*j+2] = v.z; hq[4*j+3] = v.w;
        }
#pragma unroll
        for (int v = 0; v < 10; ++v) {
            float s = 0.f;
#pragma unroll
            for (int i = 0; i < 16; ++i) {
                unsigned w = owP[v][16 * g4h + i];
                s += hq[2*i] * bflo(w) + hq[2*i+1] * bfhi(w);
            }
            s += __shfl_xor(s, 1);
            s += __shfl_xor(s, 2);
            if (g4h == 0) out[(b * 129 + 4 * tt + r) * 10 + v] = s + obS[v];
        }
    }
}

extern "C" void kernel_launch(void* const* d_in, const int* in_sizes, int n_in,
                              void* d_out, int out_size, void* d_ws, size_t ws_size,
                              hipStream_t stream) {
    const int*   x      = (const int*)d_in[0];
    const float* emb_w  = (const float*)d_in[1];
    const float* red_w  = (const float*)d_in[2];
    const float* red_b  = (const float*)d_in[3];
    const float* conv_w = (const float*)d_in[4];
    const float* conv_b = (const float*)d_in[5];
    const float* out_w  = (const float*)d_in[6];
    const float* out_b  = (const float*)d_in[7];
    (void)in_sizes; (void)n_in; (void)ws_size; (void)out_size;
    unsigned short* gw16 = (unsigned short*)d_ws;            // 32*129*128 bf16 = 1,056,768 B
    float* tab = (float*)((char*)d_ws + GWOFF);              // 2560 f32 = 10,240 B
    vgt_tab<<<10, 256, 0, stream>>>(emb_w, red_w, tab);
    vgt_phase1<<<128, 256, 0, stream>>>(x, red_b, conv_w, conv_b, tab, gw16);
    vgt_phase2<<<128, 512, 0, stream>>>(conv_w, conv_b, out_w, out_b, gw16, (float*)d_out);
}

// Round 18
// 170.126 us; speedup vs baseline: 1.0754x; 1.0754x over previous
//
#include <hip/hip_runtime.h>

typedef __attribute__((ext_vector_type(8))) short short8;
typedef __attribute__((ext_vector_type(4))) float f32x4;
typedef __attribute__((ext_vector_type(16))) float f32x16;

#define I2ROWS 40
#define I2STRIDE (I2ROWS * 128)     // 5120 shorts / buffer (phase 2)
#define P1ROWS 72
#define P1STRIDE (P1ROWS * 128)     // 9216 shorts / buffer (phase 1)
#define GWOFF 1056768               // byte offset of tab[] in d_ws (after gw16)

template<int N> struct IC { static constexpr int v = N; };

static __device__ __forceinline__ unsigned packbf(float hi, float lo) {
    return __builtin_amdgcn_perm(__float_as_uint(hi) + 0x8000u,
                                 __float_as_uint(lo) + 0x8000u, 0x07060302u);
}
static __device__ __forceinline__ unsigned short one_bf(float f) {
    return (unsigned short)((__float_as_uint(f) + 0x8000u) >> 16);
}
static __device__ __forceinline__ float bflo(unsigned u) { return __uint_as_float(u << 16); }
static __device__ __forceinline__ float bfhi(unsigned u) { return __uint_as_float(u & 0xffff0000u); }

// bf16 image swizzle: 8-short (16B) granular XOR
static __device__ __forceinline__ int swzB(int row, int c) {
    return row * 128 + (c ^ ((row & 15) << 3));
}
// fp32 master swizzle (phase 1): 2-float granular XOR
static __device__ __forceinline__ int swzH(int t, int o) {
    return (t * 128 + o) ^ ((t & 15) << 1);
}

// ============ KERNEL 0: embedding+reducer collapsed tables (weight-only) ============
__global__ __launch_bounds__(256, 1)
void vgt_tab(const float* __restrict__ emb_w, const float* __restrict__ red_w,
             float* __restrict__ tab)
{
    int i = blockIdx.x * 256 + threadIdx.x;
    if (i >= 2560) return;
    int o = i / 20, col = i % 20, v = (col < 10) ? col : (col - 10);
    const float4* rw = (const float4*)(red_w + o * 256 + ((col < 10) ? 0 : 128));
    const float4* ew = (const float4*)(emb_w + v * 128);
    float s = 0.f;
#pragma unroll 8
    for (int c2 = 0; c2 < 32; ++c2) {
        float4 a = rw[c2], e = ew[c2];
        s += a.x * e.x + a.y * e.y + a.z * e.z + a.w * e.w;
    }
    tab[i] = s;
}

// ============ PHASE 1: steps 0-7 chunked with halo, 128 blocks x 256 thr ============
__global__ __launch_bounds__(256, 1)
void vgt_phase1(const int* __restrict__ x,
                const float* __restrict__ red_b,
                const float* __restrict__ conv_w,
                const float* __restrict__ conv_b,
                const float* __restrict__ tab,
                unsigned short* __restrict__ gw16)
{
    __shared__ short imgC[2 * P1STRIDE];   // 36864 B ping-pong, rows = t - ws + 2
    __shared__ float hrFC[64 * 128];       // 32768 B fp32 master, rows = t - ws
    __shared__ float tabS[2560];
    __shared__ float cbS[128];
    __shared__ float rbS[128];
    __shared__ int   xbS[256];

    const int bid = blockIdx.x, b = bid >> 2, c = bid & 3;
    const int os = c * 33, oe = (os + 33 > 129) ? 129 : (os + 33), ws = os - 14;
    const int tid = threadIdx.x, lane = tid & 63;
    const int wm = tid >> 6, obase = wm * 32;
    const int l31 = lane & 31, lhi = lane >> 5;

    for (int i = tid; i < P1STRIDE; i += 256) ((int*)imgC)[i] = 0;   // both buffers
    for (int i = tid; i < 2560; i += 256) tabS[i] = tab[i];
    xbS[tid] = x[b * 256 + tid];
    if (tid < 128) { cbS[tid] = conv_b[tid]; rbS[tid] = red_b[tid]; }

    short8 aw[24];
#pragma unroll
    for (int s = 0; s < 24; ++s) {
        int kk = s >> 3, cb = s & 7;
        int o = obase + l31, c0 = cb * 16 + lhi * 8;
        short8 v;
#pragma unroll
        for (int j = 0; j < 8; ++j)
            v[j] = (short)one_bf(conv_w[(o * 128 + c0 + j) * 3 + kk]);
        aw[s] = v;
    }
    __syncthreads();

    for (int i = tid; i < 68 * 64; i += 256) {
        int rr = i >> 6, o2 = (i & 63) * 2, t = ws - 2 + rr;
        float v0 = 0.f, v1 = 0.f;
        if (t >= 0 && t < 128) {
            int x1 = xbS[t], x2 = xbS[t + 128];
            v0 = tabS[o2 * 20 + x1] + tabS[o2 * 20 + 10 + x2] + rbS[o2];
            v0 = v0 > 0.f ? v0 : 0.f;
            v1 = tabS[(o2 + 1) * 20 + x1] + tabS[(o2 + 1) * 20 + 10 + x2] + rbS[o2 + 1];
            v1 = v1 > 0.f ? v1 : 0.f;
            *(unsigned*)&imgC[swzB(rr, o2)] = packbf(v1, v0);
        }
        int rm = rr - 2;
        if (rm >= 0 && rm < 64) *(float2*)&hrFC[swzH(rm, o2)] = make_float2(v0, v1);
    }
    __syncthreads();

    int cur = 0;
    auto tileC = [&](auto DDC, int n, const short* src, short* dst) {
        constexpr int DD = decltype(DDC)::v;
        f32x16 a0, a1, a2;
#pragma unroll
        for (int g = 0; g < 4; ++g) {
            float4 bv = *(const float4*)&cbS[obase + 8 * g + 4 * lhi];
            a0[4*g+0] = bv.x; a0[4*g+1] = bv.y; a0[4*g+2] = bv.z; a0[4*g+3] = bv.w;
            a1[4*g+0] = 0.f; a1[4*g+1] = 0.f; a1[4*g+2] = 0.f; a1[4*g+3] = 0.f;
            a2[4*g+0] = 0.f; a2[4*g+1] = 0.f; a2[4*g+2] = 0.f; a2[4*g+3] = 0.f;
        }
        const int rb0 = n * 32 + l31 + 2 - DD;
#define TAPC(KK, ACC) { const int row = rb0 + KK * DD; \
    _Pragma("unroll") for (int cb = 0; cb < 8; ++cb) { \
        short8 bf = *(const short8*)&src[swzB(row, cb * 16 + lhi * 8)]; \
        ACC = __builtin_amdgcn_mfma_f32_32x32x16_bf16(aw[KK * 8 + cb], bf, ACC, 0, 0, 0); } }
        TAPC(0, a0) TAPC(1, a1) TAPC(2, a2)
#undef TAPC
        const int t = ws + n * 32 + l31;
        if (t >= 0 && t <= 128) {
            const int rm = n * 32 + l31;
#pragma unroll
            for (int g = 0; g < 4; ++g) {
                const int o4 = obase + 8 * g + 4 * lhi;
                const int h0 = swzH(rm, o4), h1 = swzH(rm, o4 + 2);
                float2 ha = *(const float2*)&hrFC[h0];
                float2 hb = *(const float2*)&hrFC[h1];
                ha.x += fmaxf(a0[4*g+0] + a1[4*g+0] + a2[4*g+0], 0.f);
                ha.y += fmaxf(a0[4*g+1] + a1[4*g+1] + a2[4*g+1], 0.f);
                hb.x += fmaxf(a0[4*g+2] + a1[4*g+2] + a2[4*g+2], 0.f);
                hb.y += fmaxf(a0[4*g+3] + a1[4*g+3] + a2[4*g+3], 0.f);
                *(float2*)&hrFC[h0] = ha;
                *(float2*)&hrFC[h1] = hb;
                *(uint2*)&dst[swzB(rm + 2, o4)] =
                    make_uint2(packbf(ha.y, ha.x), packbf(hb.y, hb.x));
            }
        }
    };
    auto step1 = [&](auto DDC) {
        const short* src = imgC + cur * P1STRIDE;
        short*       dst = imgC + (cur ^ 1) * P1STRIDE;
        tileC(DDC, 0, src, dst);
        tileC(DDC, 1, src, dst);
        __syncthreads();
        cur ^= 1;
    };
    for (int i = 0; i < 4; ++i) step1(IC<1>{});
    for (int i = 0; i < 4; ++i) step1(IC<2>{});

    for (int i = tid; i < (oe - os) * 128; i += 256) {
        int t = os + (i >> 7), o = i & 127;
        gw16[b * 16512 + t * 128 + o] = one_bf(hrFC[swzH(t - ws, o)]);
    }
}

// ===== PHASE 2: 123 d=4 steps on residue lattices, 128 blocks x 512 thr (8 waves, 16x16x32) =====
__global__ __launch_bounds__(512, 1)
void vgt_phase2(const float* __restrict__ conv_w,
                const float* __restrict__ conv_b,
                const float* __restrict__ out_w,
                const float* __restrict__ out_b,
                const unsigned short* __restrict__ gw16,
                float* __restrict__ out)
{
    __shared__ short    img2[2 * I2STRIDE];   // 20480 B ping-pong; rows 0, 34+ stay zero
    __shared__ float    hrF2[33 * 128];       // final h slice (plain layout)
    __shared__ unsigned owP[10][64];
    __shared__ float    cbS[128];
    __shared__ float    obS[16];

    const int bid = blockIdx.x, b = bid >> 2, r = bid & 3;
    const int tid = threadIdx.x, lane = tid & 63;
    const int wv = tid >> 6;          // 0..7 = 16-o tile
    const int obase = wv * 16;
    const int l15 = lane & 15, g4 = lane >> 4;   // g4: 0..3

    for (int i = tid; i < I2STRIDE; i += 512) ((int*)img2)[i] = 0;   // both buffers
    if (tid < 128) cbS[tid] = conv_b[tid];
    if (tid < 16)  obS[tid] = (tid < 10) ? out_b[tid] : 0.f;
    for (int i = tid; i < 640; i += 512) {
        int v = i >> 6, j = i & 63;
        owP[v][j] = packbf(out_w[v * 128 + 2 * j + 1], out_w[v * 128 + 2 * j]);
    }

    // A fragments 16x16x32: aw[kk*4+kb], lane holds A[obase+l15][kb*32+g4*8+j] (48 VGPR)
    short8 aw[12];
#pragma unroll
    for (int s = 0; s < 12; ++s) {
        int kk = s >> 2, kb = s & 3;
        int o = obase + l15, c0 = kb * 32 + g4 * 8;
        short8 v;
#pragma unroll
        for (int j = 0; j < 8; ++j)
            v[j] = (short)one_bf(conv_w[(o * 128 + c0 + j) * 3 + kk]);
        aw[s] = v;
    }

    // fp32 masters in registers (16x16 C layout: o = obase+g4*4+q, t' = tt*16+l15)
    const unsigned short* gb = gw16 + b * 16512;
    float hm[2][4], hA[4];
#pragma unroll
    for (int tt = 0; tt < 2; ++tt) {
        int tp = tt * 16 + l15;
#pragma unroll
        for (int q = 0; q < 4; ++q)
            hm[tt][q] = bflo((unsigned)gb[(4 * tp + r) * 128 + obase + g4 * 4 + q]);
    }
#pragma unroll
    for (int q = 0; q < 4; ++q)
        hA[q] = (r == 0) ? bflo((unsigned)gb[16384 + obase + g4 * 4 + q]) : 0.f;

    // resident LDS byte addresses (tt=1 = +4096 imm; buffer flip = +10240 imm)
    int aM[12], aA[8], aWr, aWA;
#pragma unroll
    for (int s = 0; s < 12; ++s)
        aM[s] = 2 * swzB(l15 + (s >> 2), (s & 3) * 32 + g4 * 8);
#pragma unroll
    for (int s = 0; s < 8; ++s)
        aA[s] = 2 * swzB(32 + (s >> 2), (s & 3) * 32 + g4 * 8);
    aWr = 2 * swzB(l15 + 1, obase + g4 * 4);
    aWA = 2 * swzB(33, obase + g4 * 4);

    __syncthreads();   // img2 zeroed, cbS ready

    float bias4[4];
#pragma unroll
    for (int q = 0; q < 4; ++q) bias4[q] = cbS[obase + g4 * 4 + q];

    // populate img2 buffer 0
    for (int i = tid; i < 33 * 64; i += 512) {
        int tp = i >> 6, o2 = (i & 63) * 2;
        if (tp < 32) {
            unsigned u0 = gb[(4 * tp + r) * 128 + o2], u1 = gb[(4 * tp + r) * 128 + o2 + 1];
            *(unsigned*)&img2[swzB(tp + 1, o2)] = (u1 << 16) | u0;
        } else if (r == 0) {
            unsigned u0 = gb[16384 + o2], u1 = gb[16384 + o2 + 1];
            *(unsigned*)&img2[swzB(33, o2)] = (u1 << 16) | u0;
        }
    }
    __syncthreads();

    char* const ibase = (char*)img2;

    auto stepF = [&](auto SO_, auto DO_) {
        constexpr int SO = decltype(SO_)::v;
        constexpr int DO = decltype(DO_)::v;
        f32x4 c00, c01, c10, c11;
#pragma unroll
        for (int q = 0; q < 4; ++q) {
            c00[q] = bias4[q]; c10[q] = bias4[q];
            c01[q] = 0.f; c11[q] = 0.f;
        }
#pragma unroll
        for (int s = 0; s < 8; ++s) {           // taps 0,1
            short8 b0 = *(const short8*)(ibase + aM[s] + SO);
            short8 b1 = *(const short8*)(ibase + aM[s] + 4096 + SO);
            c00 = __builtin_amdgcn_mfma_f32_16x16x32_bf16(aw[s], b0, c00, 0, 0, 0);
            c10 = __builtin_amdgcn_mfma_f32_16x16x32_bf16(aw[s], b1, c10, 0, 0, 0);
        }
#pragma unroll
        for (int s = 8; s < 12; ++s) {          // tap 2
            short8 b0 = *(const short8*)(ibase + aM[s] + SO);
            short8 b1 = *(const short8*)(ibase + aM[s] + 4096 + SO);
            c01 = __builtin_amdgcn_mfma_f32_16x16x32_bf16(aw[s], b0, c01, 0, 0, 0);
            c11 = __builtin_amdgcn_mfma_f32_16x16x32_bf16(aw[s], b1, c11, 0, 0, 0);
        }
        // commit main (register master)
        {
#pragma unroll
            for (int q = 0; q < 4; ++q) hm[0][q] += fmaxf(c00[q] + c01[q], 0.f);
            *(uint2*)(ibase + aWr + DO) =
                make_uint2(packbf(hm[0][1], hm[0][0]), packbf(hm[0][3], hm[0][2]));
#pragma unroll
            for (int q = 0; q < 4; ++q) hm[1][q] += fmaxf(c10[q] + c11[q], 0.f);
            *(uint2*)(ibase + aWr + 4096 + DO) =
                make_uint2(packbf(hm[1][1], hm[1][0]), packbf(hm[1][3], hm[1][2]));
        }
        // appendix t'=32 (r==0): taps 0,1; B reads wave-uniform -> LDS broadcast
        if (r == 0) {
            f32x4 d0, d1;
#pragma unroll
            for (int q = 0; q < 4; ++q) { d0[q] = bias4[q]; d1[q] = 0.f; }
#pragma unroll
            for (int s = 0; s < 4; ++s) {
                short8 bf = *(const short8*)(ibase + aA[s] + SO);
                d0 = __builtin_amdgcn_mfma_f32_16x16x32_bf16(aw[s], bf, d0, 0, 0, 0);
            }
#pragma unroll
            for (int s = 4; s < 8; ++s) {
                short8 bf = *(const short8*)(ibase + aA[s] + SO);
                d1 = __builtin_amdgcn_mfma_f32_16x16x32_bf16(aw[s], bf, d1, 0, 0, 0);
            }
#pragma unroll
            for (int q = 0; q < 4; ++q) hA[q] += fmaxf(d0[q] + d1[q], 0.f);
            if (l15 == 0)
                *(uint2*)(ibase + aWA + DO) =
                    make_uint2(packbf(hA[1], hA[0]), packbf(hA[3], hA[2]));
        }
        __syncthreads();
    };

    for (int i2 = 0; i2 < 61; ++i2) {
        stepF(IC<0>{}, IC<10240>{});
        stepF(IC<10240>{}, IC<0>{});
    }
    stepF(IC<0>{}, IC<10240>{});   // 123rd step

    // dump masters to LDS (plain layout) for the head
#pragma unroll
    for (int tt = 0; tt < 2; ++tt)
        *(float4*)&hrF2[(tt * 16 + l15) * 128 + obase + g4 * 4] =
            make_float4(hm[tt][0], hm[tt][1], hm[tt][2], hm[tt][3]);
    if (r == 0 && l15 == 0)
        *(float4*)&hrF2[32 * 128 + obase + g4 * 4] =
            make_float4(hA[0], hA[1], hA[2], hA[3]);
    __syncthreads();

    // output head: out[b, 4*t'+r, v]
    const int g4h = tid & 3;
    const int tt = tid >> 2;
    const int TR = (r == 0) ? 33 : 32;
    if (tt < TR) {
        float hq[32];
#pragma unroll
        for (int j = 0; j < 8; ++j) {
            float4 v = *(const float4*)&hrF2[tt * 128 + 32 * g4h + 4 * j];
            hq[4*j+0] = v.x; hq[4*j+1] = v.y; hq[4*j+2] = v.z; hq[4*j+3] = v.w;
        }
#pragma unroll
        for (int v = 0; v < 10; ++v) {
            float s = 0.f;
#pragma unroll
            for (int i = 0; i < 16; ++i) {
                unsigned w = owP[v][16 * g4h + i];
                s += hq[2*i] * bflo(w) + hq[2*i+1] * bfhi(w);
            }
            s += __shfl_xor(s, 1);
            s += __shfl_xor(s, 2);
            if (g4h == 0) out[(b * 129 + 4 * tt + r) * 10 + v] = s + obS[v];
        }
    }
}

extern "C" void kernel_launch(void* const* d_in, const int* in_sizes, int n_in,
                              void* d_out, int out_size, void* d_ws, size_t ws_size,
                              hipStream_t stream) {
    const int*   x      = (const int*)d_in[0];
    const float* emb_w  = (const float*)d_in[1];
    const float* red_w  = (const float*)d_in[2];
    const float* red_b  = (const float*)d_in[3];
    const float* conv_w = (const float*)d_in[4];
    const float* conv_b = (const float*)d_in[5];
    const float* out_w  = (const float*)d_in[6];
    const float* out_b  = (const float*)d_in[7];
    (void)in_sizes; (void)n_in; (void)ws_size; (void)out_size;
    unsigned short* gw16 = (unsigned short*)d_ws;            // 32*129*128 bf16 = 1,056,768 B
    float* tab = (float*)((char*)d_ws + GWOFF);              // 2560 f32 = 10,240 B
    vgt_tab<<<10, 256, 0, stream>>>(emb_w, red_w, tab);
    vgt_phase1<<<128, 256, 0, stream>>>(x, red_b, conv_w, conv_b, tab, gw16);
    vgt_phase2<<<128, 512, 0, stream>>>(conv_w, conv_b, out_w, out_b, gw16, (float*)d_out);
}